// Round 15
// baseline (105.567 us; speedup 1.0000x reference)
//
#include <hip/hip_runtime.h>
#include <cstdint>
#include <cstddef>

namespace {

constexpr int BATCH = 4;
constexpr int LQ = 2048;
constexpr int LK = 2048;
constexpr int D = 512;
constexpr int MQ = BATCH * LQ;

using f16 = _Float16;
typedef _Float16 f16x8 __attribute__((ext_vector_type(8)));
typedef _Float16 f16x4 __attribute__((ext_vector_type(4)));
typedef float f32x4 __attribute__((ext_vector_type(4)));

__device__ __forceinline__ f16x8 cvt8(const float4 a, const float4 b) {
  f16x8 h;
  h[0] = (f16)a.x; h[1] = (f16)a.y; h[2] = (f16)a.z; h[3] = (f16)a.w;
  h[4] = (f16)b.x; h[5] = (f16)b.y; h[6] = (f16)b.z; h[7] = (f16)b.w;
  return h;
}

typedef __attribute__((address_space(1))) const void gas_void;
typedef __attribute__((address_space(3))) void las_void;
__device__ __forceinline__ void gload_lds16(const void* g, void* l) {
  __builtin_amdgcn_global_load_lds((gas_void*)g, (las_void*)l, 16, 0, 0);
}

// ---------------------------------------------------------------------------
// prep: flat-grid fusion of {q-transform, k-transform, v-transpose}.
// (BK=32 version — R10 proven; BK=64 regressed in R14.)
// ---------------------------------------------------------------------------
__global__ __launch_bounds__(256) void prep_kernel(
    const float* __restrict__ query, const float* __restrict__ keyp,
    const float* __restrict__ value, const float* __restrict__ Wq,
    const float* __restrict__ Wk, const float* __restrict__ bq,
    const float* __restrict__ bk, f16* __restrict__ qh, f16* __restrict__ kh,
    float* __restrict__ qnsqp, float* __restrict__ knsqp,
    f16* __restrict__ vt) {
  __shared__ __align__(16) char smem[21504];
  const int bid0 = blockIdx.x;
  const int t = threadIdx.x;

  if (bid0 >= 512) {
    // ---- v-transpose: 64x64 tile ----
    const int bid = bid0 - 512;
    const int kt = bid & 31;
    const int dt = (bid >> 5) & 7;
    const int b = bid >> 8;
    const int k0 = kt * 64, d0 = dt * 64;
    f16(*T)[72] = reinterpret_cast<f16(*)[72]>(smem);
#pragma unroll
    for (int i = 0; i < 4; ++i) {
      const int u = t + i * 256;
      const int k = u >> 4;
      const int d4 = (u & 15) << 2;
      float4 x = *reinterpret_cast<const float4*>(
          value + (size_t)(b * LK + k0 + k) * D + d0 + d4);
      T[d4 + 0][k] = (f16)x.x;
      T[d4 + 1][k] = (f16)x.y;
      T[d4 + 2][k] = (f16)x.z;
      T[d4 + 3][k] = (f16)x.w;
    }
    __syncthreads();
#pragma unroll
    for (int i = 0; i < 2; ++i) {
      const int u = t + i * 256;
      const int d = u >> 3;
      const int k8 = (u & 7) << 3;
      f16x8 h = *reinterpret_cast<const f16x8*>(&T[d][k8]);
      *reinterpret_cast<f16x8*>(vt + (size_t)(b * D + d0 + d) * LK + k0 + k8) =
          h;
    }
    return;
  }

  // ---- tanh-transform ----
  const int which = bid0 >> 8;
  const float* __restrict__ X = which ? keyp : query;
  const float* __restrict__ W = which ? Wk : Wq;
  const float* __restrict__ bias = which ? bk : bq;
  f16* __restrict__ out = which ? kh : qh;
  float* __restrict__ nsqp = which ? knsqp : qnsqp;

  const int bid = bid0 & 255;
  const int tm = bid & 63;
  const int tn = bid >> 6;
  const int brow = tm * 128, bcol = tn * 128;
  const int lane = t & 63;
  const int wid = t >> 6;
  const int wr = (wid >> 1) * 64, wc = (wid & 1) * 64;
  const int lr = lane & 15;
  const int lk = (lane >> 4) << 3;
  const int g4 = (lane >> 4) << 2;

  f16(*As)[40] = reinterpret_cast<f16(*)[40]>(smem);
  f16(*Bs)[40] = reinterpret_cast<f16(*)[40]>(smem + 10240);
  float(*s_ss)[2] = reinterpret_cast<float(*)[2]>(smem + 20480);

  f32x4 acc[4][4] = {};

  for (int k0 = 0; k0 < D; k0 += 32) {
#pragma unroll
    for (int i = 0; i < 2; ++i) {
      const int u = t + i * 256;
      const int r = u >> 2;
      const int c8 = (u & 3) << 3;
      const float4* pa =
          reinterpret_cast<const float4*>(X + (size_t)(brow + r) * D + k0 + c8);
      *reinterpret_cast<f16x8*>(&As[r][c8]) = cvt8(pa[0], pa[1]);
      const float4* pb =
          reinterpret_cast<const float4*>(W + (size_t)(bcol + r) * D + k0 + c8);
      *reinterpret_cast<f16x8*>(&Bs[r][c8]) = cvt8(pb[0], pb[1]);
    }
    __syncthreads();
    f16x8 af[4], bf[4];
#pragma unroll
    for (int m = 0; m < 4; ++m)
      af[m] = *reinterpret_cast<const f16x8*>(&As[wr + m * 16 + lr][lk]);
#pragma unroll
    for (int n = 0; n < 4; ++n)
      bf[n] = *reinterpret_cast<const f16x8*>(&Bs[wc + n * 16 + lr][lk]);
#pragma unroll
    for (int m = 0; m < 4; ++m)
#pragma unroll
      for (int n = 0; n < 4; ++n)
        acc[m][n] =
            __builtin_amdgcn_mfma_f32_16x16x32_f16(bf[n], af[m], acc[m][n], 0, 0, 0);
    __syncthreads();
  }

  float4 bv[4];
#pragma unroll
  for (int n = 0; n < 4; ++n)
    bv[n] = *reinterpret_cast<const float4*>(&bias[bcol + wc + n * 16 + g4]);

#pragma unroll
  for (int m = 0; m < 4; ++m) {
    const int row = brow + wr + m * 16 + lr;
    float ss = 0.f;
#pragma unroll
    for (int n = 0; n < 4; ++n) {
      float th[4];
#pragma unroll
      for (int r = 0; r < 4; ++r) {
        th[r] = tanhf(acc[m][n][r] + ((const float*)&bv[n])[r]);
        ss = fmaf(th[r], th[r], ss);
      }
      f16x4 h4;
      h4[0] = (f16)th[0]; h4[1] = (f16)th[1];
      h4[2] = (f16)th[2]; h4[3] = (f16)th[3];
      *reinterpret_cast<f16x4*>(out + (size_t)row * D + bcol + wc + n * 16 + g4) =
          h4;
    }
    ss += __shfl_xor(ss, 16);
    ss += __shfl_xor(ss, 32);
    if (lane < 16) s_ss[wr + m * 16 + lr][wid & 1] = ss;
  }
  __syncthreads();
  if (t < 128) nsqp[(size_t)(brow + t) * 4 + tn] = s_ss[t][0] + s_ss[t][1];
}

// ---------------------------------------------------------------------------
// scores: s = dot*(w0 + w1*rq*rk) - w2*sqrt(max(qn2+kn2-2dot,0))
// RAW16: store e = (f16)exp(s - M_tile) -> sraw; tstats = (M_tile, expsum).
// else:  store raw f32 s -> attn, tstats same.
// XCD-swizzled grid (1024 = 8 x 128).
// ---------------------------------------------------------------------------
template <bool RAW16>
__global__ __launch_bounds__(256, 4) void scores_kernel(
    const f16* __restrict__ qh, const f16* __restrict__ kh,
    const float* __restrict__ qnsqp, const float* __restrict__ knsqp,
    const float* __restrict__ sw, float* __restrict__ attn,
    f16* __restrict__ sraw, float2* __restrict__ tstats) {
  const int bid0 = blockIdx.x;
  const int bid = (bid0 & 7) * 128 + (bid0 >> 3);  // XCD-contiguous chunks
  const int tn = bid & 15;
  const int tm = (bid >> 4) & 15;
  const int b = bid >> 8;
  const int brow = tm * 128, bcol = tn * 128;
  const int t = threadIdx.x;
  const int lane = t & 63;
  const int wid = t >> 6;
  const int wr = (wid >> 1) * 64, wc = (wid & 1) * 64;
  const int lr = lane & 15;
  const int lk = (lane >> 4) << 3;
  const int g4 = (lane >> 4) << 2;

  __shared__ f16 As[128 * 64];
  __shared__ f16 Bs[128 * 64];
  __shared__ float s_m[128][2];
  __shared__ float s_l[128][2];

  f32x4 acc[4][4] = {};

  const int srow = lane >> 3;
  const int scol = ((lane & 7) ^ srow) << 4;
  const char* aBase = (const char*)(qh + (size_t)(b * LQ + brow) * D);
  const char* bBase = (const char*)(kh + (size_t)(b * LK + bcol) * D);
  const int swz = (lr & 7) << 4;

  for (int k0 = 0; k0 < D; k0 += 64) {
#pragma unroll
    for (int i = 0; i < 4; ++i) {
      const int chunk = wid * 4 + i;
      const int row = chunk * 8 + srow;
      gload_lds16(aBase + (size_t)row * (D * 2) + k0 * 2 + scol,
                  (char*)As + chunk * 1024);
      gload_lds16(bBase + (size_t)row * (D * 2) + k0 * 2 + scol,
                  (char*)Bs + chunk * 1024);
    }
    __syncthreads();
    f16x8 af[2][4], bf[2][4];
#pragma unroll
    for (int h = 0; h < 2; ++h) {
      const int cb = h * 64 + lk * 2;
#pragma unroll
      for (int m = 0; m < 4; ++m)
        af[h][m] = *(const f16x8*)((const char*)As + (wr + m * 16 + lr) * 128 +
                                   (cb ^ swz));
#pragma unroll
      for (int n = 0; n < 4; ++n)
        bf[h][n] = *(const f16x8*)((const char*)Bs + (wc + n * 16 + lr) * 128 +
                                   (cb ^ swz));
    }
#pragma unroll
    for (int h = 0; h < 2; ++h)
#pragma unroll
      for (int m = 0; m < 4; ++m)
#pragma unroll
        for (int n = 0; n < 4; ++n)
          acc[m][n] = __builtin_amdgcn_mfma_f32_16x16x32_f16(bf[h][n], af[h][m],
                                                             acc[m][n], 0, 0, 0);
    __syncthreads();
  }

  const float s0 = sw[0], s1 = sw[1], s2 = sw[2];
  const float smx = fmaxf(s0, fmaxf(s1, s2));
  float w0 = __expf(s0 - smx), w1 = __expf(s1 - smx), w2 = __expf(s2 - smx);
  const float winv = 1.f / (w0 + w1 + w2);
  w0 *= winv; w1 *= winv; w2 *= winv;

  float qn2_[4], w1rq[4];
#pragma unroll
  for (int m = 0; m < 4; ++m) {
    const float4 qp = *reinterpret_cast<const float4*>(
        &qnsqp[(size_t)(b * LQ + brow + wr + m * 16 + lr) * 4]);
    const float v = (qp.x + qp.y) + (qp.z + qp.w);
    qn2_[m] = v;
    w1rq[m] = w1 * rsqrtf(fmaxf(v, 1e-16f));
  }
  float kn2[4][4], rk[4][4];
#pragma unroll
  for (int n = 0; n < 4; ++n) {
#pragma unroll
    for (int r = 0; r < 4; ++r) {
      const int col = bcol + wc + n * 16 + g4 + r;
      const float4 kp = *reinterpret_cast<const float4*>(
          &knsqp[(size_t)(b * LK + col) * 4]);
      const float v = (kp.x + kp.y) + (kp.z + kp.w);
      kn2[n][r] = v;
      rk[n][r] = rsqrtf(fmaxf(v, 1e-16f));
    }
  }

  // pass 1: scores into acc, per-row half-tile max -> LDS
#pragma unroll
  for (int m = 0; m < 4; ++m) {
    const int rl = wr + m * 16 + lr;
    const int row = brow + rl;
    float mx = -3.4e38f;
#pragma unroll
    for (int n = 0; n < 4; ++n) {
      float4 o;
#pragma unroll
      for (int r = 0; r < 4; ++r) {
        const float dot = acc[m][n][r];
        const float qk2 = qn2_[m] + kn2[n][r];
        const float st = sqrtf(fmaxf(qk2 - 2.f * dot, 0.f));
        const float c = fmaf(w1rq[m], rk[n][r], w0);
        const float s = fmaf(dot, c, -w2 * st);
        ((float*)&o)[r] = s;
        acc[m][n][r] = s;
        mx = fmaxf(mx, s);
      }
      if constexpr (!RAW16) {
        *reinterpret_cast<float4*>(attn + (size_t)(b * LQ + row) * LK + bcol +
                                   wc + n * 16 + g4) = o;
      }
    }
    mx = fmaxf(mx, __shfl_xor(mx, 16));
    mx = fmaxf(mx, __shfl_xor(mx, 32));
    if (lane < 16) s_m[rl][wid & 1] = mx;
  }
  __syncthreads();

  // pass 2: e = exp(s - M_tile) -> f16 store (RAW16) + expsum
#pragma unroll
  for (int m = 0; m < 4; ++m) {
    const int rl = wr + m * 16 + lr;
    const int row = brow + rl;
    const float Mt = fmaxf(s_m[rl][0], s_m[rl][1]);
    float es = 0.f;
#pragma unroll
    for (int n = 0; n < 4; ++n) {
      float e0 = __expf(acc[m][n][0] - Mt);
      float e1 = __expf(acc[m][n][1] - Mt);
      float e2 = __expf(acc[m][n][2] - Mt);
      float e3 = __expf(acc[m][n][3] - Mt);
      es += (e0 + e1) + (e2 + e3);
      if constexpr (RAW16) {
        f16x4 h4;
        h4[0] = (f16)e0; h4[1] = (f16)e1; h4[2] = (f16)e2; h4[3] = (f16)e3;
        *reinterpret_cast<f16x4*>(sraw + (size_t)(b * LQ + row) * LK + bcol +
                                  wc + n * 16 + g4) = h4;
      }
    }
    es += __shfl_xor(es, 16);
    es += __shfl_xor(es, 32);
    if (lane < 16) s_l[rl][wid & 1] = es;
  }
  __syncthreads();
  if (t < 128) {
    tstats[(size_t)(b * LQ + brow + t) * 16 + tn] =
        make_float2(fmaxf(s_m[t][0], s_m[t][1]), s_l[t][0] + s_l[t][1]);
  }
}

// ---------------------------------------------------------------------------
// normalize (fallback only, !useA16): combine tstats -> M, invL; f32 in-place.
// ---------------------------------------------------------------------------
__global__ __launch_bounds__(256) void normalize_kernel(
    float* __restrict__ attn, const float2* __restrict__ tstats) {
  const int row = blockIdx.x;
  const int t = threadIdx.x;
  __shared__ float sM, sI;
  if (t < 16) {
    float2 st = tstats[(size_t)row * 16 + t];
    float M = st.x;
    M = fmaxf(M, __shfl_xor(M, 8));
    M = fmaxf(M, __shfl_xor(M, 4));
    M = fmaxf(M, __shfl_xor(M, 2));
    M = fmaxf(M, __shfl_xor(M, 1));
    float l = st.y * __expf(st.x - M);
    l += __shfl_xor(l, 8);
    l += __shfl_xor(l, 4);
    l += __shfl_xor(l, 2);
    l += __shfl_xor(l, 1);
    if (t == 0) { sM = M; sI = 1.f / l; }
  }
  __syncthreads();
  const float M = sM, invL = sI;
  float* rp = attn + (size_t)row * LK + t * 8;
  float4 v0 = *reinterpret_cast<const float4*>(rp);
  float4 v1 = *reinterpret_cast<const float4*>(rp + 4);
  v0.x = __expf(v0.x - M) * invL; v0.y = __expf(v0.y - M) * invL;
  v0.z = __expf(v0.z - M) * invL; v0.w = __expf(v0.w - M) * invL;
  v1.x = __expf(v1.x - M) * invL; v1.y = __expf(v1.y - M) * invL;
  v1.z = __expf(v1.z - M) * invL; v1.w = __expf(v1.w - M) * invL;
  *reinterpret_cast<float4*>(rp) = v0;
  *reinterpret_cast<float4*>(rp + 4) = v1;
}

// ---------------------------------------------------------------------------
// pv: ctx = p @ v. Block 128x128 (BM=128 halves B-panel staging traffic),
// BK=64, 1024 threads = 16 waves (8M x 2N), wave tile 16x64 (R10's proven
// wave shape), grid 256 = 1 block/CU (16 waves/CU, same occupancy as R10),
// XCD-swizzled (8 x 32). Single-buffered, A-register prefetch.
// NORM: per-(row,tile) scale (f32 sScale); A-staging = e16 * scale (pk_mul);
// block tn stores f32 attn for its column-quarter (balanced).
// ---------------------------------------------------------------------------
template <bool NORM>
__global__ __launch_bounds__(1024, 2) void pv_kernel(
    float* __restrict__ attnf, const f16* __restrict__ sraw,
    const f16* __restrict__ vt, const float2* __restrict__ tstats,
    float* __restrict__ ctx) {
  const int bid0 = blockIdx.x;
  const int bid = (bid0 & 7) * 32 + (bid0 >> 3);  // 256 = 8 x 32
  const int tn = bid & 3;          // D/128
  const int tm = (bid >> 2) & 15;  // LQ/128
  const int b = bid >> 6;
  const int brow = tm * 128, bcol = tn * 128;
  const int t = threadIdx.x;
  const int lane = t & 63;
  const int wid = t >> 6;                        // 0..15
  const int wr = (wid >> 1) * 16, wc = (wid & 1) * 64;
  const int lr = lane & 15;
  const int lk = (lane >> 4) << 3;
  const int g4 = (lane >> 4) << 2;

  __shared__ f16 As[128 * 64];       // 16 KB
  __shared__ f16 Bs[128 * 64];       // 16 KB
  __shared__ float sScale[128][17];  // ~8.7 KB

  f32x4 acc[4] = {};

  const int srow = lane >> 3;
  const int scol = ((lane & 7) ^ srow) << 4;
  const size_t arow0 = (size_t)(b * LQ + brow);
  const char* bBase = (const char*)(vt + (size_t)(b * D + bcol) * LK);
  const int swz = (lr & 7) << 4;

  // A staging geometry: one f16x8 per thread per K-step (128 rows x 64 cols).
  const int arow = t >> 3;                   // 0..127
  const int c16 = (t & 7) << 4;              // dest byte col in As row
  const int csrc = c16 ^ ((arow & 7) << 4);  // swizzled source byte col
  const char* aRow =
      (const char*)sraw + (arow0 + arow) * (size_t)LK * 2 + csrc;

  if constexpr (NORM) {
    if (t < 512) {
      const int prow = t >> 2;  // 0..127
      const int j4 = (t & 3) * 4;
      const float4* tp =
          reinterpret_cast<const float4*>(&tstats[(arow0 + prow) * 16 + j4]);
      const float4 a = tp[0], c = tp[1];
      float m_ = fmaxf(fmaxf(a.x, a.z), fmaxf(c.x, c.z));
      m_ = fmaxf(m_, __shfl_xor(m_, 1));
      m_ = fmaxf(m_, __shfl_xor(m_, 2));
      float l_ = a.y * __expf(a.x - m_) + a.w * __expf(a.z - m_) +
                 c.y * __expf(c.x - m_) + c.w * __expf(c.z - m_);
      l_ += __shfl_xor(l_, 1);
      l_ += __shfl_xor(l_, 2);
      const float invL = 1.f / l_;
      sScale[prow][j4 + 0] = __expf(a.x - m_) * invL;
      sScale[prow][j4 + 1] = __expf(a.z - m_) * invL;
      sScale[prow][j4 + 2] = __expf(c.x - m_) * invL;
      sScale[prow][j4 + 3] = __expf(c.z - m_) * invL;
    }
    __syncthreads();
  }

  f16x8 hcur;
  if constexpr (NORM) hcur = *(const f16x8*)(aRow);

  for (int k0 = 0; k0 < LK; k0 += 64) {
    // B staging: async, one gload_lds per thread (16 chunks of 8 rows).
    {
      const int chunk = wid;
      const int row = chunk * 8 + srow;
      gload_lds16(bBase + (size_t)row * (LK * 2) + k0 * 2 + scol,
                  (char*)Bs + chunk * 1024);
    }
    if constexpr (NORM) {
      // prefetch next K-step's e-values (rides the same vmcnt drain as B)
      f16x8 hnext;
      if (k0 + 64 < LK) hnext = *(const f16x8*)(aRow + (k0 + 64) * 2);
      const float sc = sScale[arow][k0 >> 7];
      const f16 sch = (f16)sc;
      const f16x8 scv = {sch, sch, sch, sch, sch, sch, sch, sch};
      const f16x8 hv = hcur * scv;  // p = e * scale  (v_pk_mul_f16, no exp)
      *(f16x8*)((char*)As + arow * 128 + c16) = hv;
      if ((k0 >> 9) == tn) {  // this block's column-quarter: f32 attn out
        float4 e0, e1;
        e0.x = (float)hv[0]; e0.y = (float)hv[1];
        e0.z = (float)hv[2]; e0.w = (float)hv[3];
        e1.x = (float)hv[4]; e1.y = (float)hv[5];
        e1.z = (float)hv[6]; e1.w = (float)hv[7];
        float* op = attnf + (arow0 + arow) * LK + k0 + (csrc >> 1);
        *reinterpret_cast<float4*>(op) = e0;
        *reinterpret_cast<float4*>(op + 4) = e1;
      }
      hcur = hnext;
    } else {
      const float4* ps = (const float4*)((const char*)attnf +
                                         ((arow0 + arow) * LK + k0) * 4 +
                                         csrc * 2);
      *(f16x8*)((char*)As + arow * 128 + c16) = cvt8(ps[0], ps[1]);
    }
    __syncthreads();
    f16x8 af[2], bf[2][4];
#pragma unroll
    for (int h = 0; h < 2; ++h) {
      const int cb = h * 64 + lk * 2;
      af[h] = *(const f16x8*)((const char*)As + (wr + lr) * 128 + (cb ^ swz));
#pragma unroll
      for (int n = 0; n < 4; ++n)
        bf[h][n] = *(const f16x8*)((const char*)Bs + (wc + n * 16 + lr) * 128 +
                                   (cb ^ swz));
    }
#pragma unroll
    for (int h = 0; h < 2; ++h)
#pragma unroll
      for (int n = 0; n < 4; ++n)
        acc[n] = __builtin_amdgcn_mfma_f32_16x16x32_f16(bf[h][n], af[h],
                                                        acc[n], 0, 0, 0);
    __syncthreads();
  }

  const int row = brow + wr + lr;
  float* rowp = ctx + (size_t)(b * LQ + row) * D + bcol + wc;
#pragma unroll
  for (int n = 0; n < 4; ++n) {
    float4 o;
    o.x = acc[n][0]; o.y = acc[n][1];
    o.z = acc[n][2]; o.w = acc[n][3];
    *reinterpret_cast<float4*>(rowp + n * 16 + g4) = o;
  }
}

}  // namespace

extern "C" void kernel_launch(void* const* d_in, const int* in_sizes, int n_in,
                              void* d_out, int out_size, void* d_ws,
                              size_t ws_size, hipStream_t stream) {
  const float* query = (const float*)d_in[0];
  const float* key = (const float*)d_in[1];
  const float* value = (const float*)d_in[2];
  const float* Wq = (const float*)d_in[3];
  const float* bq = (const float*)d_in[4];
  const float* Wk = (const float*)d_in[5];
  const float* bk = (const float*)d_in[6];
  const float* sw = (const float*)d_in[7];

  float* ctx = (float*)d_out;                            // [B,LQ,D]
  float* attn = (float*)d_out + (size_t)BATCH * LQ * D;  // [B,LQ,LK]

  char* ws = (char*)d_ws;
  f16* vt = (f16*)ws;                                    // 8 MiB
  f16* qh = (f16*)(ws + (size_t)(8u << 20));             // 8 MiB
  f16* kh = (f16*)(ws + (size_t)(16u << 20));            // 8 MiB
  float* qnsqp = (float*)(ws + (size_t)(24u << 20));     // 128 KiB
  float* knsqp = qnsqp + (size_t)MQ * 4;                 // 128 KiB
  float2* tstats = (float2*)(ws + (size_t)(25u << 20));  // 1 MiB
  f16* sraw = (f16*)(ws + (size_t)(26u << 20));          // 32 MiB
  const size_t ws_needed =
      ((size_t)(26u << 20)) + (size_t)BATCH * LQ * LK * sizeof(f16);
  const bool useA16 = ws_size >= ws_needed;

  prep_kernel<<<1536, 256, 0, stream>>>(query, key, value, Wq, Wk, bq, bk, qh,
                                        kh, qnsqp, knsqp, vt);
  if (useA16) {
    scores_kernel<true><<<1024, 256, 0, stream>>>(qh, kh, qnsqp, knsqp, sw,
                                                  attn, sraw, tstats);
    pv_kernel<true><<<256, 1024, 0, stream>>>(attn, sraw, vt, tstats, ctx);
  } else {
    scores_kernel<false><<<1024, 256, 0, stream>>>(qh, kh, qnsqp, knsqp, sw,
                                                   attn, sraw, tstats);
    normalize_kernel<<<MQ, 256, 0, stream>>>(attn, tstats);
    pv_kernel<false><<<256, 1024, 0, stream>>>(attn, sraw, vt, tstats, ctx);
  }
}

// Round 16
// 102.944 us; speedup vs baseline: 1.0255x; 1.0255x over previous
//
#include <hip/hip_runtime.h>
#include <cstdint>
#include <cstddef>

namespace {

constexpr int BATCH = 4;
constexpr int LQ = 2048;
constexpr int LK = 2048;
constexpr int D = 512;
constexpr int MQ = BATCH * LQ;

using f16 = _Float16;
typedef _Float16 f16x8 __attribute__((ext_vector_type(8)));
typedef _Float16 f16x4 __attribute__((ext_vector_type(4)));
typedef float f32x4 __attribute__((ext_vector_type(4)));

__device__ __forceinline__ f16x8 cvt8(const float4 a, const float4 b) {
  f16x8 h;
  h[0] = (f16)a.x; h[1] = (f16)a.y; h[2] = (f16)a.z; h[3] = (f16)a.w;
  h[4] = (f16)b.x; h[5] = (f16)b.y; h[6] = (f16)b.z; h[7] = (f16)b.w;
  return h;
}

typedef __attribute__((address_space(1))) const void gas_void;
typedef __attribute__((address_space(3))) void las_void;
__device__ __forceinline__ void gload_lds16(const void* g, void* l) {
  __builtin_amdgcn_global_load_lds((gas_void*)g, (las_void*)l, 16, 0, 0);
}

// ---------------------------------------------------------------------------
// prep: flat-grid fusion of {q-transform, k-transform, v-transpose}. (R10)
// ---------------------------------------------------------------------------
__global__ __launch_bounds__(256) void prep_kernel(
    const float* __restrict__ query, const float* __restrict__ keyp,
    const float* __restrict__ value, const float* __restrict__ Wq,
    const float* __restrict__ Wk, const float* __restrict__ bq,
    const float* __restrict__ bk, f16* __restrict__ qh, f16* __restrict__ kh,
    float* __restrict__ qnsqp, float* __restrict__ knsqp,
    f16* __restrict__ vt) {
  __shared__ __align__(16) char smem[21504];
  const int bid0 = blockIdx.x;
  const int t = threadIdx.x;

  if (bid0 >= 512) {
    // ---- v-transpose: 64x64 tile ----
    const int bid = bid0 - 512;
    const int kt = bid & 31;
    const int dt = (bid >> 5) & 7;
    const int b = bid >> 8;
    const int k0 = kt * 64, d0 = dt * 64;
    f16(*T)[72] = reinterpret_cast<f16(*)[72]>(smem);
#pragma unroll
    for (int i = 0; i < 4; ++i) {
      const int u = t + i * 256;
      const int k = u >> 4;
      const int d4 = (u & 15) << 2;
      float4 x = *reinterpret_cast<const float4*>(
          value + (size_t)(b * LK + k0 + k) * D + d0 + d4);
      T[d4 + 0][k] = (f16)x.x;
      T[d4 + 1][k] = (f16)x.y;
      T[d4 + 2][k] = (f16)x.z;
      T[d4 + 3][k] = (f16)x.w;
    }
    __syncthreads();
#pragma unroll
    for (int i = 0; i < 2; ++i) {
      const int u = t + i * 256;
      const int d = u >> 3;
      const int k8 = (u & 7) << 3;
      f16x8 h = *reinterpret_cast<const f16x8*>(&T[d][k8]);
      *reinterpret_cast<f16x8*>(vt + (size_t)(b * D + d0 + d) * LK + k0 + k8) =
          h;
    }
    return;
  }

  // ---- tanh-transform ----
  const int which = bid0 >> 8;
  const float* __restrict__ X = which ? keyp : query;
  const float* __restrict__ W = which ? Wk : Wq;
  const float* __restrict__ bias = which ? bk : bq;
  f16* __restrict__ out = which ? kh : qh;
  float* __restrict__ nsqp = which ? knsqp : qnsqp;

  const int bid = bid0 & 255;
  const int tm = bid & 63;
  const int tn = bid >> 6;
  const int brow = tm * 128, bcol = tn * 128;
  const int lane = t & 63;
  const int wid = t >> 6;
  const int wr = (wid >> 1) * 64, wc = (wid & 1) * 64;
  const int lr = lane & 15;
  const int lk = (lane >> 4) << 3;
  const int g4 = (lane >> 4) << 2;

  f16(*As)[40] = reinterpret_cast<f16(*)[40]>(smem);
  f16(*Bs)[40] = reinterpret_cast<f16(*)[40]>(smem + 10240);
  float(*s_ss)[2] = reinterpret_cast<float(*)[2]>(smem + 20480);

  f32x4 acc[4][4] = {};

  for (int k0 = 0; k0 < D; k0 += 32) {
#pragma unroll
    for (int i = 0; i < 2; ++i) {
      const int u = t + i * 256;
      const int r = u >> 2;
      const int c8 = (u & 3) << 3;
      const float4* pa =
          reinterpret_cast<const float4*>(X + (size_t)(brow + r) * D + k0 + c8);
      *reinterpret_cast<f16x8*>(&As[r][c8]) = cvt8(pa[0], pa[1]);
      const float4* pb =
          reinterpret_cast<const float4*>(W + (size_t)(bcol + r) * D + k0 + c8);
      *reinterpret_cast<f16x8*>(&Bs[r][c8]) = cvt8(pb[0], pb[1]);
    }
    __syncthreads();
    f16x8 af[4], bf[4];
#pragma unroll
    for (int m = 0; m < 4; ++m)
      af[m] = *reinterpret_cast<const f16x8*>(&As[wr + m * 16 + lr][lk]);
#pragma unroll
    for (int n = 0; n < 4; ++n)
      bf[n] = *reinterpret_cast<const f16x8*>(&Bs[wc + n * 16 + lr][lk]);
#pragma unroll
    for (int m = 0; m < 4; ++m)
#pragma unroll
      for (int n = 0; n < 4; ++n)
        acc[m][n] =
            __builtin_amdgcn_mfma_f32_16x16x32_f16(bf[n], af[m], acc[m][n], 0, 0, 0);
    __syncthreads();
  }

  float4 bv[4];
#pragma unroll
  for (int n = 0; n < 4; ++n)
    bv[n] = *reinterpret_cast<const float4*>(&bias[bcol + wc + n * 16 + g4]);

#pragma unroll
  for (int m = 0; m < 4; ++m) {
    const int row = brow + wr + m * 16 + lr;
    float ss = 0.f;
#pragma unroll
    for (int n = 0; n < 4; ++n) {
      float th[4];
#pragma unroll
      for (int r = 0; r < 4; ++r) {
        th[r] = tanhf(acc[m][n][r] + ((const float*)&bv[n])[r]);
        ss = fmaf(th[r], th[r], ss);
      }
      f16x4 h4;
      h4[0] = (f16)th[0]; h4[1] = (f16)th[1];
      h4[2] = (f16)th[2]; h4[3] = (f16)th[3];
      *reinterpret_cast<f16x4*>(out + (size_t)row * D + bcol + wc + n * 16 + g4) =
          h4;
    }
    ss += __shfl_xor(ss, 16);
    ss += __shfl_xor(ss, 32);
    if (lane < 16) s_ss[wr + m * 16 + lr][wid & 1] = ss;
  }
  __syncthreads();
  if (t < 128) nsqp[(size_t)(brow + t) * 4 + tn] = s_ss[t][0] + s_ss[t][1];
}

// ---------------------------------------------------------------------------
// scores: s = dot*(w0 + w1*rq*rk) - w2*sqrt(max(qn2+kn2-2dot,0))
// RAW16: store e = (f16)exp(s - M_tile) -> sraw; tstats = (M_tile, expsum).
// else:  store raw f32 s -> attn, tstats same.  (unchanged)
// ---------------------------------------------------------------------------
template <bool RAW16>
__global__ __launch_bounds__(256, 4) void scores_kernel(
    const f16* __restrict__ qh, const f16* __restrict__ kh,
    const float* __restrict__ qnsqp, const float* __restrict__ knsqp,
    const float* __restrict__ sw, float* __restrict__ attn,
    f16* __restrict__ sraw, float2* __restrict__ tstats) {
  const int bid0 = blockIdx.x;
  const int bid = (bid0 & 7) * 128 + (bid0 >> 3);
  const int tn = bid & 15;
  const int tm = (bid >> 4) & 15;
  const int b = bid >> 8;
  const int brow = tm * 128, bcol = tn * 128;
  const int t = threadIdx.x;
  const int lane = t & 63;
  const int wid = t >> 6;
  const int wr = (wid >> 1) * 64, wc = (wid & 1) * 64;
  const int lr = lane & 15;
  const int lk = (lane >> 4) << 3;
  const int g4 = (lane >> 4) << 2;

  __shared__ f16 As[128 * 64];
  __shared__ f16 Bs[128 * 64];
  __shared__ float s_m[128][2];
  __shared__ float s_l[128][2];

  f32x4 acc[4][4] = {};

  const int srow = lane >> 3;
  const int scol = ((lane & 7) ^ srow) << 4;
  const char* aBase = (const char*)(qh + (size_t)(b * LQ + brow) * D);
  const char* bBase = (const char*)(kh + (size_t)(b * LK + bcol) * D);
  const int swz = (lr & 7) << 4;

  for (int k0 = 0; k0 < D; k0 += 64) {
#pragma unroll
    for (int i = 0; i < 4; ++i) {
      const int chunk = wid * 4 + i;
      const int row = chunk * 8 + srow;
      gload_lds16(aBase + (size_t)row * (D * 2) + k0 * 2 + scol,
                  (char*)As + chunk * 1024);
      gload_lds16(bBase + (size_t)row * (D * 2) + k0 * 2 + scol,
                  (char*)Bs + chunk * 1024);
    }
    __syncthreads();
    f16x8 af[2][4], bf[2][4];
#pragma unroll
    for (int h = 0; h < 2; ++h) {
      const int cb = h * 64 + lk * 2;
#pragma unroll
      for (int m = 0; m < 4; ++m)
        af[h][m] = *(const f16x8*)((const char*)As + (wr + m * 16 + lr) * 128 +
                                   (cb ^ swz));
#pragma unroll
      for (int n = 0; n < 4; ++n)
        bf[h][n] = *(const f16x8*)((const char*)Bs + (wc + n * 16 + lr) * 128 +
                                   (cb ^ swz));
    }
#pragma unroll
    for (int h = 0; h < 2; ++h)
#pragma unroll
      for (int m = 0; m < 4; ++m)
#pragma unroll
        for (int n = 0; n < 4; ++n)
          acc[m][n] = __builtin_amdgcn_mfma_f32_16x16x32_f16(bf[h][n], af[h][m],
                                                             acc[m][n], 0, 0, 0);
    __syncthreads();
  }

  const float s0 = sw[0], s1 = sw[1], s2 = sw[2];
  const float smx = fmaxf(s0, fmaxf(s1, s2));
  float w0 = __expf(s0 - smx), w1 = __expf(s1 - smx), w2 = __expf(s2 - smx);
  const float winv = 1.f / (w0 + w1 + w2);
  w0 *= winv; w1 *= winv; w2 *= winv;

  float qn2_[4], w1rq[4];
#pragma unroll
  for (int m = 0; m < 4; ++m) {
    const float4 qp = *reinterpret_cast<const float4*>(
        &qnsqp[(size_t)(b * LQ + brow + wr + m * 16 + lr) * 4]);
    const float v = (qp.x + qp.y) + (qp.z + qp.w);
    qn2_[m] = v;
    w1rq[m] = w1 * rsqrtf(fmaxf(v, 1e-16f));
  }
  float kn2[4][4], rk[4][4];
#pragma unroll
  for (int n = 0; n < 4; ++n) {
#pragma unroll
    for (int r = 0; r < 4; ++r) {
      const int col = bcol + wc + n * 16 + g4 + r;
      const float4 kp = *reinterpret_cast<const float4*>(
          &knsqp[(size_t)(b * LK + col) * 4]);
      const float v = (kp.x + kp.y) + (kp.z + kp.w);
      kn2[n][r] = v;
      rk[n][r] = rsqrtf(fmaxf(v, 1e-16f));
    }
  }

  // pass 1: scores into acc, per-row half-tile max -> LDS
#pragma unroll
  for (int m = 0; m < 4; ++m) {
    const int rl = wr + m * 16 + lr;
    const int row = brow + rl;
    float mx = -3.4e38f;
#pragma unroll
    for (int n = 0; n < 4; ++n) {
      float4 o;
#pragma unroll
      for (int r = 0; r < 4; ++r) {
        const float dot = acc[m][n][r];
        const float qk2 = qn2_[m] + kn2[n][r];
        const float st = sqrtf(fmaxf(qk2 - 2.f * dot, 0.f));
        const float c = fmaf(w1rq[m], rk[n][r], w0);
        const float s = fmaf(dot, c, -w2 * st);
        ((float*)&o)[r] = s;
        acc[m][n][r] = s;
        mx = fmaxf(mx, s);
      }
      if constexpr (!RAW16) {
        *reinterpret_cast<float4*>(attn + (size_t)(b * LQ + row) * LK + bcol +
                                   wc + n * 16 + g4) = o;
      }
    }
    mx = fmaxf(mx, __shfl_xor(mx, 16));
    mx = fmaxf(mx, __shfl_xor(mx, 32));
    if (lane < 16) s_m[rl][wid & 1] = mx;
  }
  __syncthreads();

  // pass 2: e = exp(s - M_tile) -> f16 store (RAW16) + expsum
#pragma unroll
  for (int m = 0; m < 4; ++m) {
    const int rl = wr + m * 16 + lr;
    const int row = brow + rl;
    const float Mt = fmaxf(s_m[rl][0], s_m[rl][1]);
    float es = 0.f;
#pragma unroll
    for (int n = 0; n < 4; ++n) {
      float e0 = __expf(acc[m][n][0] - Mt);
      float e1 = __expf(acc[m][n][1] - Mt);
      float e2 = __expf(acc[m][n][2] - Mt);
      float e3 = __expf(acc[m][n][3] - Mt);
      es += (e0 + e1) + (e2 + e3);
      if constexpr (RAW16) {
        f16x4 h4;
        h4[0] = (f16)e0; h4[1] = (f16)e1; h4[2] = (f16)e2; h4[3] = (f16)e3;
        *reinterpret_cast<f16x4*>(sraw + (size_t)(b * LQ + row) * LK + bcol +
                                  wc + n * 16 + g4) = h4;
      }
    }
    es += __shfl_xor(es, 16);
    es += __shfl_xor(es, 32);
    if (lane < 16) s_l[rl][wid & 1] = es;
  }
  __syncthreads();
  if (t < 128) {
    tstats[(size_t)(b * LQ + brow + t) * 16 + tn] =
        make_float2(fmaxf(s_m[t][0], s_m[t][1]), s_l[t][0] + s_l[t][1]);
  }
}

// ---------------------------------------------------------------------------
// normalize (fallback only, !useA16): combine tstats -> M, invL; f32 in-place.
// ---------------------------------------------------------------------------
__global__ __launch_bounds__(256) void normalize_kernel(
    float* __restrict__ attn, const float2* __restrict__ tstats) {
  const int row = blockIdx.x;
  const int t = threadIdx.x;
  __shared__ float sM, sI;
  if (t < 16) {
    float2 st = tstats[(size_t)row * 16 + t];
    float M = st.x;
    M = fmaxf(M, __shfl_xor(M, 8));
    M = fmaxf(M, __shfl_xor(M, 4));
    M = fmaxf(M, __shfl_xor(M, 2));
    M = fmaxf(M, __shfl_xor(M, 1));
    float l = st.y * __expf(st.x - M);
    l += __shfl_xor(l, 8);
    l += __shfl_xor(l, 4);
    l += __shfl_xor(l, 2);
    l += __shfl_xor(l, 1);
    if (t == 0) { sM = M; sI = 1.f / l; }
  }
  __syncthreads();
  const float M = sM, invL = sI;
  float* rp = attn + (size_t)row * LK + t * 8;
  float4 v0 = *reinterpret_cast<const float4*>(rp);
  float4 v1 = *reinterpret_cast<const float4*>(rp + 4);
  v0.x = __expf(v0.x - M) * invL; v0.y = __expf(v0.y - M) * invL;
  v0.z = __expf(v0.z - M) * invL; v0.w = __expf(v0.w - M) * invL;
  v1.x = __expf(v1.x - M) * invL; v1.y = __expf(v1.y - M) * invL;
  v1.z = __expf(v1.z - M) * invL; v1.w = __expf(v1.w - M) * invL;
  *reinterpret_cast<float4*>(rp) = v0;
  *reinterpret_cast<float4*>(rp + 4) = v1;
}

// ---------------------------------------------------------------------------
// pv: ctx = p @ v. R10 geometry (64x128 tile, BK=64, 512 thr, 8 waves of
// 16x64, grid 512, 16 waves/CU). NEW: NORM A-staging is pure gload_lds
// (pre-swizzled source); the softmax scale is applied on the af FRAGMENT
// (row-uniform -> per-lane scalar pk_mul) inside the MFMA phase; f32 attn
// written from the scaled fragment by (wid&1)==0 waves for the block's
// column-quarter. Staging phase = 3 async gload_lds, zero VALU chain.
// ---------------------------------------------------------------------------
template <bool NORM>
__global__ __launch_bounds__(512, 4) void pv_kernel(
    float* __restrict__ attnf, const f16* __restrict__ sraw,
    const f16* __restrict__ vt, const float2* __restrict__ tstats,
    float* __restrict__ ctx) {
  const int bid0 = blockIdx.x;
  const int bid = (bid0 & 7) * 64 + (bid0 >> 3);  // 512 = 8 x 64
  const int tn = bid & 3;          // D/128
  const int tm = (bid >> 2) & 31;  // LQ/64
  const int b = bid >> 7;
  const int brow = tm * 64, bcol = tn * 128;
  const int t = threadIdx.x;
  const int lane = t & 63;
  const int wid = t >> 6;                       // 0..7
  const int wr = (wid >> 1) * 16, wc = (wid & 1) * 64;
  const int lr = lane & 15;
  const int lk = (lane >> 4) << 3;
  const int g4 = (lane >> 4) << 2;

  __shared__ f16 As[64 * 64];       // 8 KB
  __shared__ f16 Bs[128 * 64];      // 16 KB
  __shared__ float sScale[64][17];  // per-(row, col-tile) combined scale

  f32x4 acc[4] = {};

  const int srow = lane >> 3;
  const int scol = ((lane & 7) ^ srow) << 4;
  const size_t arow0 = (size_t)(b * LQ + brow);
  const char* bBase = (const char*)(vt + (size_t)(b * D + bcol) * LK);
  const char* aBase = (const char*)sraw + arow0 * (size_t)LK * 2;
  const int swz = (lr & 7) << 4;

  if constexpr (NORM) {
    if (t < 256) {
      const int prow = t >> 2;  // 0..63
      const int j4 = (t & 3) * 4;
      const float4* tp =
          reinterpret_cast<const float4*>(&tstats[(arow0 + prow) * 16 + j4]);
      const float4 a = tp[0], c = tp[1];
      float m_ = fmaxf(fmaxf(a.x, a.z), fmaxf(c.x, c.z));
      m_ = fmaxf(m_, __shfl_xor(m_, 1));
      m_ = fmaxf(m_, __shfl_xor(m_, 2));
      float l_ = a.y * __expf(a.x - m_) + a.w * __expf(a.z - m_) +
                 c.y * __expf(c.x - m_) + c.w * __expf(c.z - m_);
      l_ += __shfl_xor(l_, 1);
      l_ += __shfl_xor(l_, 2);
      const float invL = 1.f / l_;
      sScale[prow][j4 + 0] = __expf(a.x - m_) * invL;
      sScale[prow][j4 + 1] = __expf(a.z - m_) * invL;
      sScale[prow][j4 + 2] = __expf(c.x - m_) * invL;
      sScale[prow][j4 + 3] = __expf(c.z - m_) * invL;
    }
    __syncthreads();
  }

  // reg-staged path geometry (fallback only)
  const int arow = t >> 3;                   // 0..63
  const int c16 = (t & 7) << 4;
  const int csrc = c16 ^ ((arow & 7) << 4);

  const bool attn_owner = ((wid & 1) == 0);

  for (int k0 = 0; k0 < LK; k0 += 64) {
    if constexpr (NORM) {
      // A staging: 1 async gload_lds per thread (8 chunks of 8 rows).
      {
        const int row = wid * 8 + srow;
        gload_lds16(aBase + (size_t)row * (LK * 2) + k0 * 2 + scol,
                    (char*)As + wid * 1024);
      }
    } else {
      const float4* ps = (const float4*)((const char*)attnf +
                                         ((arow0 + arow) * LK + k0) * 4 +
                                         csrc * 2);
      *(f16x8*)((char*)As + arow * 128 + c16) = cvt8(ps[0], ps[1]);
    }
    // B staging: 2 async gload_lds per thread (16 chunks of 8 rows).
#pragma unroll
    for (int i = 0; i < 2; ++i) {
      const int chunk = wid * 2 + i;
      const int row = chunk * 8 + srow;
      gload_lds16(bBase + (size_t)row * (LK * 2) + k0 * 2 + scol,
                  (char*)Bs + chunk * 1024);
    }
    __syncthreads();
    f16x8 af[2], bf[2][4];
#pragma unroll
    for (int h = 0; h < 2; ++h) {
      const int cb = h * 64 + lk * 2;
      af[h] = *(const f16x8*)((const char*)As + (wr + lr) * 128 + (cb ^ swz));
#pragma unroll
      for (int n = 0; n < 4; ++n)
        bf[h][n] = *(const f16x8*)((const char*)Bs + (wc + n * 16 + lr) * 128 +
                                   (cb ^ swz));
    }
    if constexpr (NORM) {
      // scale the A fragment: row-uniform -> per-lane scalar multiply
      const f16 sch = (f16)sScale[wr + lr][k0 >> 7];
      const f16x8 scv = {sch, sch, sch, sch, sch, sch, sch, sch};
      af[0] = af[0] * scv;
      af[1] = af[1] * scv;
    }
#pragma unroll
    for (int h = 0; h < 2; ++h)
#pragma unroll
      for (int n = 0; n < 4; ++n)
        acc[n] = __builtin_amdgcn_mfma_f32_16x16x32_f16(bf[h][n], af[h],
                                                        acc[n], 0, 0, 0);
    if constexpr (NORM) {
      // f32 attn output from the scaled fragment: rows covered once by the
      // (wid&1)==0 waves; cols h*32+lk..+7 of this K-step; quarter == tn.
      if (attn_owner && (k0 >> 9) == tn) {
        float* op = attnf + (arow0 + wr + lr) * LK + k0;
#pragma unroll
        for (int h = 0; h < 2; ++h) {
          float4 e0, e1;
          e0.x = (float)af[h][0]; e0.y = (float)af[h][1];
          e0.z = (float)af[h][2]; e0.w = (float)af[h][3];
          e1.x = (float)af[h][4]; e1.y = (float)af[h][5];
          e1.z = (float)af[h][6]; e1.w = (float)af[h][7];
          *reinterpret_cast<float4*>(op + h * 32 + lk) = e0;
          *reinterpret_cast<float4*>(op + h * 32 + lk + 4) = e1;
        }
      }
    }
    __syncthreads();
  }

  const int row = brow + wr + lr;
  float* rowp = ctx + (size_t)(b * LQ + row) * D + bcol + wc;
#pragma unroll
  for (int n = 0; n < 4; ++n) {
    float4 o;
    o.x = acc[n][0]; o.y = acc[n][1];
    o.z = acc[n][2]; o.w = acc[n][3];
    *reinterpret_cast<float4*>(rowp + n * 16 + g4) = o;
  }
}

}  // namespace

extern "C" void kernel_launch(void* const* d_in, const int* in_sizes, int n_in,
                              void* d_out, int out_size, void* d_ws,
                              size_t ws_size, hipStream_t stream) {
  const float* query = (const float*)d_in[0];
  const float* key = (const float*)d_in[1];
  const float* value = (const float*)d_in[2];
  const float* Wq = (const float*)d_in[3];
  const float* bq = (const float*)d_in[4];
  const float* Wk = (const float*)d_in[5];
  const float* bk = (const float*)d_in[6];
  const float* sw = (const float*)d_in[7];

  float* ctx = (float*)d_out;                            // [B,LQ,D]
  float* attn = (float*)d_out + (size_t)BATCH * LQ * D;  // [B,LQ,LK]

  char* ws = (char*)d_ws;
  f16* vt = (f16*)ws;                                    // 8 MiB
  f16* qh = (f16*)(ws + (size_t)(8u << 20));             // 8 MiB
  f16* kh = (f16*)(ws + (size_t)(16u << 20));            // 8 MiB
  float* qnsqp = (float*)(ws + (size_t)(24u << 20));     // 128 KiB
  float* knsqp = qnsqp + (size_t)MQ * 4;                 // 128 KiB
  float2* tstats = (float2*)(ws + (size_t)(25u << 20));  // 1 MiB
  f16* sraw = (f16*)(ws + (size_t)(26u << 20));          // 32 MiB
  const size_t ws_needed =
      ((size_t)(26u << 20)) + (size_t)BATCH * LQ * LK * sizeof(f16);
  const bool useA16 = ws_size >= ws_needed;

  prep_kernel<<<1536, 256, 0, stream>>>(query, key, value, Wq, Wk, bq, bk, qh,
                                        kh, qnsqp, knsqp, vt);
  if (useA16) {
    scores_kernel<true><<<1024, 256, 0, stream>>>(qh, kh, qnsqp, knsqp, sw,
                                                  attn, sraw, tstats);
    pv_kernel<true><<<512, 512, 0, stream>>>(attn, sraw, vt, tstats, ctx);
  } else {
    scores_kernel<false><<<1024, 256, 0, stream>>>(qh, kh, qnsqp, knsqp, sw,
                                                   attn, sraw, tstats);
    normalize_kernel<<<MQ, 256, 0, stream>>>(attn, tstats);
    pv_kernel<false><<<512, 512, 0, stream>>>(attn, sraw, vt, tstats, ctx);
  }
}

// Round 17
// 99.026 us; speedup vs baseline: 1.0661x; 1.0396x over previous
//
#include <hip/hip_runtime.h>
#include <cstdint>
#include <cstddef>

namespace {

constexpr int BATCH = 4;
constexpr int LQ = 2048;
constexpr int LK = 2048;
constexpr int D = 512;
constexpr int MQ = BATCH * LQ;

using f16 = _Float16;
typedef _Float16 f16x8 __attribute__((ext_vector_type(8)));
typedef _Float16 f16x4 __attribute__((ext_vector_type(4)));
typedef float f32x4 __attribute__((ext_vector_type(4)));

__device__ __forceinline__ f16x8 cvt8(const float4 a, const float4 b) {
  f16x8 h;
  h[0] = (f16)a.x; h[1] = (f16)a.y; h[2] = (f16)a.z; h[3] = (f16)a.w;
  h[4] = (f16)b.x; h[5] = (f16)b.y; h[6] = (f16)b.z; h[7] = (f16)b.w;
  return h;
}

typedef __attribute__((address_space(1))) const void gas_void;
typedef __attribute__((address_space(3))) void las_void;
__device__ __forceinline__ void gload_lds16(const void* g, void* l) {
  __builtin_amdgcn_global_load_lds((gas_void*)g, (las_void*)l, 16, 0, 0);
}

// ---------------------------------------------------------------------------
// prep: flat-grid fusion of {q-transform, k-transform, v-transpose}.
// Transform: register-prefetch of next K-step's global loads (latency spans
// the MFMA phase instead of sitting serial after the barrier).
// ---------------------------------------------------------------------------
__global__ __launch_bounds__(256) void prep_kernel(
    const float* __restrict__ query, const float* __restrict__ keyp,
    const float* __restrict__ value, const float* __restrict__ Wq,
    const float* __restrict__ Wk, const float* __restrict__ bq,
    const float* __restrict__ bk, f16* __restrict__ qh, f16* __restrict__ kh,
    float* __restrict__ qnsqp, float* __restrict__ knsqp,
    f16* __restrict__ vt) {
  __shared__ __align__(16) char smem[21504];
  const int bid0 = blockIdx.x;
  const int t = threadIdx.x;

  if (bid0 >= 512) {
    // ---- v-transpose: 64x64 tile ----
    const int bid = bid0 - 512;
    const int kt = bid & 31;
    const int dt = (bid >> 5) & 7;
    const int b = bid >> 8;
    const int k0 = kt * 64, d0 = dt * 64;
    f16(*T)[72] = reinterpret_cast<f16(*)[72]>(smem);
#pragma unroll
    for (int i = 0; i < 4; ++i) {
      const int u = t + i * 256;
      const int k = u >> 4;
      const int d4 = (u & 15) << 2;
      float4 x = *reinterpret_cast<const float4*>(
          value + (size_t)(b * LK + k0 + k) * D + d0 + d4);
      T[d4 + 0][k] = (f16)x.x;
      T[d4 + 1][k] = (f16)x.y;
      T[d4 + 2][k] = (f16)x.z;
      T[d4 + 3][k] = (f16)x.w;
    }
    __syncthreads();
#pragma unroll
    for (int i = 0; i < 2; ++i) {
      const int u = t + i * 256;
      const int d = u >> 3;
      const int k8 = (u & 7) << 3;
      f16x8 h = *reinterpret_cast<const f16x8*>(&T[d][k8]);
      *reinterpret_cast<f16x8*>(vt + (size_t)(b * D + d0 + d) * LK + k0 + k8) =
          h;
    }
    return;
  }

  // ---- tanh-transform ----
  const int which = bid0 >> 8;
  const float* __restrict__ X = which ? keyp : query;
  const float* __restrict__ W = which ? Wk : Wq;
  const float* __restrict__ bias = which ? bk : bq;
  f16* __restrict__ out = which ? kh : qh;
  float* __restrict__ nsqp = which ? knsqp : qnsqp;

  const int bid = bid0 & 255;
  const int tm = bid & 63;
  const int tn = bid >> 6;
  const int brow = tm * 128, bcol = tn * 128;
  const int lane = t & 63;
  const int wid = t >> 6;
  const int wr = (wid >> 1) * 64, wc = (wid & 1) * 64;
  const int lr = lane & 15;
  const int lk = (lane >> 4) << 3;
  const int g4 = (lane >> 4) << 2;

  f16(*As)[40] = reinterpret_cast<f16(*)[40]>(smem);
  f16(*Bs)[40] = reinterpret_cast<f16(*)[40]>(smem + 10240);
  float(*s_ss)[2] = reinterpret_cast<float(*)[2]>(smem + 20480);

  f32x4 acc[4][4] = {};

  // staging geometry: 2 units of 8 f32 per panel per thread
  const int r0 = t >> 2;
  const int c0 = (t & 3) << 3;
  const int r1 = (t + 256) >> 2;
  const int c1 = ((t + 256) & 3) << 3;
  const float* pa0 = X + (size_t)(brow + r0) * D + c0;
  const float* pa1 = X + (size_t)(brow + r1) * D + c1;
  const float* pb0 = W + (size_t)(bcol + r0) * D + c0;
  const float* pb1 = W + (size_t)(bcol + r1) * D + c1;

  float4 la0[2], la1[2], lb0[2], lb1[2];
  la0[0] = reinterpret_cast<const float4*>(pa0)[0];
  la0[1] = reinterpret_cast<const float4*>(pa0)[1];
  la1[0] = reinterpret_cast<const float4*>(pa1)[0];
  la1[1] = reinterpret_cast<const float4*>(pa1)[1];
  lb0[0] = reinterpret_cast<const float4*>(pb0)[0];
  lb0[1] = reinterpret_cast<const float4*>(pb0)[1];
  lb1[0] = reinterpret_cast<const float4*>(pb1)[0];
  lb1[1] = reinterpret_cast<const float4*>(pb1)[1];

  for (int k0 = 0; k0 < D; k0 += 32) {
    // write current prefetched registers to LDS
    *reinterpret_cast<f16x8*>(&As[r0][c0]) = cvt8(la0[0], la0[1]);
    *reinterpret_cast<f16x8*>(&As[r1][c1]) = cvt8(la1[0], la1[1]);
    *reinterpret_cast<f16x8*>(&Bs[r0][c0]) = cvt8(lb0[0], lb0[1]);
    *reinterpret_cast<f16x8*>(&Bs[r1][c1]) = cvt8(lb1[0], lb1[1]);
    // issue next step's loads (latency hides under MFMA below)
    if (k0 + 32 < D) {
      const int kn = k0 + 32;
      la0[0] = reinterpret_cast<const float4*>(pa0 + kn)[0];
      la0[1] = reinterpret_cast<const float4*>(pa0 + kn)[1];
      la1[0] = reinterpret_cast<const float4*>(pa1 + kn)[0];
      la1[1] = reinterpret_cast<const float4*>(pa1 + kn)[1];
      lb0[0] = reinterpret_cast<const float4*>(pb0 + kn)[0];
      lb0[1] = reinterpret_cast<const float4*>(pb0 + kn)[1];
      lb1[0] = reinterpret_cast<const float4*>(pb1 + kn)[0];
      lb1[1] = reinterpret_cast<const float4*>(pb1 + kn)[1];
    }
    __syncthreads();
    f16x8 af[4], bf[4];
#pragma unroll
    for (int m = 0; m < 4; ++m)
      af[m] = *reinterpret_cast<const f16x8*>(&As[wr + m * 16 + lr][lk]);
#pragma unroll
    for (int n = 0; n < 4; ++n)
      bf[n] = *reinterpret_cast<const f16x8*>(&Bs[wc + n * 16 + lr][lk]);
#pragma unroll
    for (int m = 0; m < 4; ++m)
#pragma unroll
      for (int n = 0; n < 4; ++n)
        acc[m][n] =
            __builtin_amdgcn_mfma_f32_16x16x32_f16(bf[n], af[m], acc[m][n], 0, 0, 0);
    __syncthreads();
  }

  float4 bv[4];
#pragma unroll
  for (int n = 0; n < 4; ++n)
    bv[n] = *reinterpret_cast<const float4*>(&bias[bcol + wc + n * 16 + g4]);

#pragma unroll
  for (int m = 0; m < 4; ++m) {
    const int row = brow + wr + m * 16 + lr;
    float ss = 0.f;
#pragma unroll
    for (int n = 0; n < 4; ++n) {
      float th[4];
#pragma unroll
      for (int r = 0; r < 4; ++r) {
        th[r] = tanhf(acc[m][n][r] + ((const float*)&bv[n])[r]);
        ss = fmaf(th[r], th[r], ss);
      }
      f16x4 h4;
      h4[0] = (f16)th[0]; h4[1] = (f16)th[1];
      h4[2] = (f16)th[2]; h4[3] = (f16)th[3];
      *reinterpret_cast<f16x4*>(out + (size_t)row * D + bcol + wc + n * 16 + g4) =
          h4;
    }
    ss += __shfl_xor(ss, 16);
    ss += __shfl_xor(ss, 32);
    if (lane < 16) s_ss[wr + m * 16 + lr][wid & 1] = ss;
  }
  __syncthreads();
  if (t < 128) nsqp[(size_t)(brow + t) * 4 + tn] = s_ss[t][0] + s_ss[t][1];
}

// ---------------------------------------------------------------------------
// scores: s = dot*(w0 + w1*rq*rk) - w2*sqrt(max(qn2+kn2-2dot,0))
// RAW16: store e = (f16)exp(s - M_tile) -> sraw; tstats = (M_tile, expsum).
// else:  store raw f32 s -> attn, tstats same.  (unchanged)
// ---------------------------------------------------------------------------
template <bool RAW16>
__global__ __launch_bounds__(256, 4) void scores_kernel(
    const f16* __restrict__ qh, const f16* __restrict__ kh,
    const float* __restrict__ qnsqp, const float* __restrict__ knsqp,
    const float* __restrict__ sw, float* __restrict__ attn,
    f16* __restrict__ sraw, float2* __restrict__ tstats) {
  const int bid0 = blockIdx.x;
  const int bid = (bid0 & 7) * 128 + (bid0 >> 3);
  const int tn = bid & 15;
  const int tm = (bid >> 4) & 15;
  const int b = bid >> 8;
  const int brow = tm * 128, bcol = tn * 128;
  const int t = threadIdx.x;
  const int lane = t & 63;
  const int wid = t >> 6;
  const int wr = (wid >> 1) * 64, wc = (wid & 1) * 64;
  const int lr = lane & 15;
  const int lk = (lane >> 4) << 3;
  const int g4 = (lane >> 4) << 2;

  __shared__ f16 As[128 * 64];
  __shared__ f16 Bs[128 * 64];
  __shared__ float s_m[128][2];
  __shared__ float s_l[128][2];

  f32x4 acc[4][4] = {};

  const int srow = lane >> 3;
  const int scol = ((lane & 7) ^ srow) << 4;
  const char* aBase = (const char*)(qh + (size_t)(b * LQ + brow) * D);
  const char* bBase = (const char*)(kh + (size_t)(b * LK + bcol) * D);
  const int swz = (lr & 7) << 4;

  for (int k0 = 0; k0 < D; k0 += 64) {
#pragma unroll
    for (int i = 0; i < 4; ++i) {
      const int chunk = wid * 4 + i;
      const int row = chunk * 8 + srow;
      gload_lds16(aBase + (size_t)row * (D * 2) + k0 * 2 + scol,
                  (char*)As + chunk * 1024);
      gload_lds16(bBase + (size_t)row * (D * 2) + k0 * 2 + scol,
                  (char*)Bs + chunk * 1024);
    }
    __syncthreads();
    f16x8 af[2][4], bf[2][4];
#pragma unroll
    for (int h = 0; h < 2; ++h) {
      const int cb = h * 64 + lk * 2;
#pragma unroll
      for (int m = 0; m < 4; ++m)
        af[h][m] = *(const f16x8*)((const char*)As + (wr + m * 16 + lr) * 128 +
                                   (cb ^ swz));
#pragma unroll
      for (int n = 0; n < 4; ++n)
        bf[h][n] = *(const f16x8*)((const char*)Bs + (wc + n * 16 + lr) * 128 +
                                   (cb ^ swz));
    }
#pragma unroll
    for (int h = 0; h < 2; ++h)
#pragma unroll
      for (int m = 0; m < 4; ++m)
#pragma unroll
        for (int n = 0; n < 4; ++n)
          acc[m][n] = __builtin_amdgcn_mfma_f32_16x16x32_f16(bf[h][n], af[h][m],
                                                             acc[m][n], 0, 0, 0);
    __syncthreads();
  }

  const float s0 = sw[0], s1 = sw[1], s2 = sw[2];
  const float smx = fmaxf(s0, fmaxf(s1, s2));
  float w0 = __expf(s0 - smx), w1 = __expf(s1 - smx), w2 = __expf(s2 - smx);
  const float winv = 1.f / (w0 + w1 + w2);
  w0 *= winv; w1 *= winv; w2 *= winv;

  float qn2_[4], w1rq[4];
#pragma unroll
  for (int m = 0; m < 4; ++m) {
    const float4 qp = *reinterpret_cast<const float4*>(
        &qnsqp[(size_t)(b * LQ + brow + wr + m * 16 + lr) * 4]);
    const float v = (qp.x + qp.y) + (qp.z + qp.w);
    qn2_[m] = v;
    w1rq[m] = w1 * rsqrtf(fmaxf(v, 1e-16f));
  }
  float kn2[4][4], rk[4][4];
#pragma unroll
  for (int n = 0; n < 4; ++n) {
#pragma unroll
    for (int r = 0; r < 4; ++r) {
      const int col = bcol + wc + n * 16 + g4 + r;
      const float4 kp = *reinterpret_cast<const float4*>(
          &knsqp[(size_t)(b * LK + col) * 4]);
      const float v = (kp.x + kp.y) + (kp.z + kp.w);
      kn2[n][r] = v;
      rk[n][r] = rsqrtf(fmaxf(v, 1e-16f));
    }
  }

  // pass 1: scores into acc, per-row half-tile max -> LDS
#pragma unroll
  for (int m = 0; m < 4; ++m) {
    const int rl = wr + m * 16 + lr;
    const int row = brow + rl;
    float mx = -3.4e38f;
#pragma unroll
    for (int n = 0; n < 4; ++n) {
      float4 o;
#pragma unroll
      for (int r = 0; r < 4; ++r) {
        const float dot = acc[m][n][r];
        const float qk2 = qn2_[m] + kn2[n][r];
        const float st = sqrtf(fmaxf(qk2 - 2.f * dot, 0.f));
        const float c = fmaf(w1rq[m], rk[n][r], w0);
        const float s = fmaf(dot, c, -w2 * st);
        ((float*)&o)[r] = s;
        acc[m][n][r] = s;
        mx = fmaxf(mx, s);
      }
      if constexpr (!RAW16) {
        *reinterpret_cast<float4*>(attn + (size_t)(b * LQ + row) * LK + bcol +
                                   wc + n * 16 + g4) = o;
      }
    }
    mx = fmaxf(mx, __shfl_xor(mx, 16));
    mx = fmaxf(mx, __shfl_xor(mx, 32));
    if (lane < 16) s_m[rl][wid & 1] = mx;
  }
  __syncthreads();

  // pass 2: e = exp(s - M_tile) -> f16 store (RAW16) + expsum
#pragma unroll
  for (int m = 0; m < 4; ++m) {
    const int rl = wr + m * 16 + lr;
    const int row = brow + rl;
    const float Mt = fmaxf(s_m[rl][0], s_m[rl][1]);
    float es = 0.f;
#pragma unroll
    for (int n = 0; n < 4; ++n) {
      float e0 = __expf(acc[m][n][0] - Mt);
      float e1 = __expf(acc[m][n][1] - Mt);
      float e2 = __expf(acc[m][n][2] - Mt);
      float e3 = __expf(acc[m][n][3] - Mt);
      es += (e0 + e1) + (e2 + e3);
      if constexpr (RAW16) {
        f16x4 h4;
        h4[0] = (f16)e0; h4[1] = (f16)e1; h4[2] = (f16)e2; h4[3] = (f16)e3;
        *reinterpret_cast<f16x4*>(sraw + (size_t)(b * LQ + row) * LK + bcol +
                                  wc + n * 16 + g4) = h4;
      }
    }
    es += __shfl_xor(es, 16);
    es += __shfl_xor(es, 32);
    if (lane < 16) s_l[rl][wid & 1] = es;
  }
  __syncthreads();
  if (t < 128) {
    tstats[(size_t)(b * LQ + brow + t) * 16 + tn] =
        make_float2(fmaxf(s_m[t][0], s_m[t][1]), s_l[t][0] + s_l[t][1]);
  }
}

// ---------------------------------------------------------------------------
// normalize (fallback only, !useA16): combine tstats -> M, invL; f32 in-place.
// ---------------------------------------------------------------------------
__global__ __launch_bounds__(256) void normalize_kernel(
    float* __restrict__ attn, const float2* __restrict__ tstats) {
  const int row = blockIdx.x;
  const int t = threadIdx.x;
  __shared__ float sM, sI;
  if (t < 16) {
    float2 st = tstats[(size_t)row * 16 + t];
    float M = st.x;
    M = fmaxf(M, __shfl_xor(M, 8));
    M = fmaxf(M, __shfl_xor(M, 4));
    M = fmaxf(M, __shfl_xor(M, 2));
    M = fmaxf(M, __shfl_xor(M, 1));
    float l = st.y * __expf(st.x - M);
    l += __shfl_xor(l, 8);
    l += __shfl_xor(l, 4);
    l += __shfl_xor(l, 2);
    l += __shfl_xor(l, 1);
    if (t == 0) { sM = M; sI = 1.f / l; }
  }
  __syncthreads();
  const float M = sM, invL = sI;
  float* rp = attn + (size_t)row * LK + t * 8;
  float4 v0 = *reinterpret_cast<const float4*>(rp);
  float4 v1 = *reinterpret_cast<const float4*>(rp + 4);
  v0.x = __expf(v0.x - M) * invL; v0.y = __expf(v0.y - M) * invL;
  v0.z = __expf(v0.z - M) * invL; v0.w = __expf(v0.w - M) * invL;
  v1.x = __expf(v1.x - M) * invL; v1.y = __expf(v1.y - M) * invL;
  v1.z = __expf(v1.z - M) * invL; v1.w = __expf(v1.w - M) * invL;
  *reinterpret_cast<float4*>(rp) = v0;
  *reinterpret_cast<float4*>(rp + 4) = v1;
}

// ---------------------------------------------------------------------------
// pv (exact R10 config, proven best): 64x128 tile, BK=64, 512 threads
// (8 waves, wave tile 16x64), grid 512 (2 blocks/CU = 16 waves/CU),
// single-buffered, A-register prefetch. NORM: per-(row,tile) scale (f32
// sScale); A-staging = e16 * scale (pk_mul); block tn stores f32 attn for
// its column-quarter (balanced).
// ---------------------------------------------------------------------------
template <bool NORM>
__global__ __launch_bounds__(512, 4) void pv_kernel(
    float* __restrict__ attnf, const f16* __restrict__ sraw,
    const f16* __restrict__ vt, const float2* __restrict__ tstats,
    float* __restrict__ ctx) {
  const int bid0 = blockIdx.x;
  const int bid = (bid0 & 7) * 64 + (bid0 >> 3);  // 512 = 8 x 64
  const int tn = bid & 3;          // D/128
  const int tm = (bid >> 2) & 31;  // LQ/64
  const int b = bid >> 7;
  const int brow = tm * 64, bcol = tn * 128;
  const int t = threadIdx.x;
  const int lane = t & 63;
  const int wid = t >> 6;                       // 0..7
  const int wr = (wid >> 1) * 16, wc = (wid & 1) * 64;
  const int lr = lane & 15;
  const int lk = (lane >> 4) << 3;
  const int g4 = (lane >> 4) << 2;

  __shared__ f16 As[64 * 64];       // 8 KB
  __shared__ f16 Bs[128 * 64];      // 16 KB
  __shared__ float sScale[64][17];  // per-(row, col-tile) combined scale

  f32x4 acc[4] = {};

  const int srow = lane >> 3;
  const int scol = ((lane & 7) ^ srow) << 4;
  const size_t arow0 = (size_t)(b * LQ + brow);
  const char* bBase = (const char*)(vt + (size_t)(b * D + bcol) * LK);
  const int swz = (lr & 7) << 4;

  // A staging geometry: one f16x8 per thread per K-step (64 rows x 64 cols).
  const int arow = t >> 3;                   // 0..63
  const int c16 = (t & 7) << 4;              // dest byte col in As row
  const int csrc = c16 ^ ((arow & 7) << 4);  // swizzled source byte col
  const char* aRow =
      (const char*)sraw + (arow0 + arow) * (size_t)LK * 2 + csrc;

  if constexpr (NORM) {
    if (t < 256) {
      const int prow = t >> 2;  // 0..63
      const int j4 = (t & 3) * 4;
      const float4* tp =
          reinterpret_cast<const float4*>(&tstats[(arow0 + prow) * 16 + j4]);
      const float4 a = tp[0], c = tp[1];
      float m_ = fmaxf(fmaxf(a.x, a.z), fmaxf(c.x, c.z));
      m_ = fmaxf(m_, __shfl_xor(m_, 1));
      m_ = fmaxf(m_, __shfl_xor(m_, 2));
      float l_ = a.y * __expf(a.x - m_) + a.w * __expf(a.z - m_) +
                 c.y * __expf(c.x - m_) + c.w * __expf(c.z - m_);
      l_ += __shfl_xor(l_, 1);
      l_ += __shfl_xor(l_, 2);
      const float invL = 1.f / l_;
      sScale[prow][j4 + 0] = __expf(a.x - m_) * invL;
      sScale[prow][j4 + 1] = __expf(a.z - m_) * invL;
      sScale[prow][j4 + 2] = __expf(c.x - m_) * invL;
      sScale[prow][j4 + 3] = __expf(c.z - m_) * invL;
    }
    __syncthreads();
  }

  f16x8 hcur;
  if constexpr (NORM) hcur = *(const f16x8*)(aRow);

  for (int k0 = 0; k0 < LK; k0 += 64) {
    // B staging: async, issued first so its latency spans the A processing.
#pragma unroll
    for (int i = 0; i < 2; ++i) {
      const int chunk = wid * 2 + i;  // 16 chunks of 8 rows
      const int row = chunk * 8 + srow;
      gload_lds16(bBase + (size_t)row * (LK * 2) + k0 * 2 + scol,
                  (char*)Bs + chunk * 1024);
    }
    if constexpr (NORM) {
      // prefetch next K-step's e-values (rides the same vmcnt drain as B)
      f16x8 hnext;
      if (k0 + 64 < LK) hnext = *(const f16x8*)(aRow + (k0 + 64) * 2);
      const float sc = sScale[arow][k0 >> 7];
      const f16 sch = (f16)sc;
      const f16x8 scv = {sch, sch, sch, sch, sch, sch, sch, sch};
      const f16x8 hv = hcur * scv;  // p = e * scale  (v_pk_mul_f16, no exp)
      *(f16x8*)((char*)As + arow * 128 + c16) = hv;
      if ((k0 >> 9) == tn) {  // this block's column-quarter: f32 attn out
        float4 e0, e1;
        e0.x = (float)hv[0]; e0.y = (float)hv[1];
        e0.z = (float)hv[2]; e0.w = (float)hv[3];
        e1.x = (float)hv[4]; e1.y = (float)hv[5];
        e1.z = (float)hv[6]; e1.w = (float)hv[7];
        float* op = attnf + (arow0 + arow) * LK + k0 + (csrc >> 1);
        *reinterpret_cast<float4*>(op) = e0;
        *reinterpret_cast<float4*>(op + 4) = e1;
      }
      hcur = hnext;
    } else {
      const float4* ps = (const float4*)((const char*)attnf +
                                         ((arow0 + arow) * LK + k0) * 4 +
                                         csrc * 2);
      *(f16x8*)((char*)As + arow * 128 + c16) = cvt8(ps[0], ps[1]);
    }
    __syncthreads();
    f16x8 af[2], bf[2][4];
#pragma unroll
    for (int h = 0; h < 2; ++h) {
      const int cb = h * 64 + lk * 2;
      af[h] = *(const f16x8*)((const char*)As + (wr + lr) * 128 + (cb ^ swz));
#pragma unroll
      for (int n = 0; n < 4; ++n)
        bf[h][n] = *(const f16x8*)((const char*)Bs + (wc + n * 16 + lr) * 128 +
                                   (cb ^ swz));
    }
#pragma unroll
    for (int h = 0; h < 2; ++h)
#pragma unroll
      for (int n = 0; n < 4; ++n)
        acc[n] = __builtin_amdgcn_mfma_f32_16x16x32_f16(bf[h][n], af[h],
                                                        acc[n], 0, 0, 0);
    __syncthreads();
  }

  const int row = brow + wr + lr;
  float* rowp = ctx + (size_t)(b * LQ + row) * D + bcol + wc;
#pragma unroll
  for (int n = 0; n < 4; ++n) {
    float4 o;
    o.x = acc[n][0]; o.y = acc[n][1];
    o.z = acc[n][2]; o.w = acc[n][3];
    *reinterpret_cast<float4*>(rowp + n * 16 + g4) = o;
  }
}

}  // namespace

extern "C" void kernel_launch(void* const* d_in, const int* in_sizes, int n_in,
                              void* d_out, int out_size, void* d_ws,
                              size_t ws_size, hipStream_t stream) {
  const float* query = (const float*)d_in[0];
  const float* key = (const float*)d_in[1];
  const float* value = (const float*)d_in[2];
  const float* Wq = (const float*)d_in[3];
  const float* bq = (const float*)d_in[4];
  const float* Wk = (const float*)d_in[5];
  const float* bk = (const float*)d_in[6];
  const float* sw = (const float*)d_in[7];

  float* ctx = (float*)d_out;                            // [B,LQ,D]
  float* attn = (float*)d_out + (size_t)BATCH * LQ * D;  // [B,LQ,LK]

  char* ws = (char*)d_ws;
  f16* vt = (f16*)ws;                                    // 8 MiB
  f16* qh = (f16*)(ws + (size_t)(8u << 20));             // 8 MiB
  f16* kh = (f16*)(ws + (size_t)(16u << 20));            // 8 MiB
  float* qnsqp = (float*)(ws + (size_t)(24u << 20));     // 128 KiB
  float* knsqp = qnsqp + (size_t)MQ * 4;                 // 128 KiB
  float2* tstats = (float2*)(ws + (size_t)(25u << 20));  // 1 MiB
  f16* sraw = (f16*)(ws + (size_t)(26u << 20));          // 32 MiB
  const size_t ws_needed =
      ((size_t)(26u << 20)) + (size_t)BATCH * LQ * LK * sizeof(f16);
  const bool useA16 = ws_size >= ws_needed;

  prep_kernel<<<1536, 256, 0, stream>>>(query, key, value, Wq, Wk, bq, bk, qh,
                                        kh, qnsqp, knsqp, vt);
  if (useA16) {
    scores_kernel<true><<<1024, 256, 0, stream>>>(qh, kh, qnsqp, knsqp, sw,
                                                  attn, sraw, tstats);
    pv_kernel<true><<<512, 512, 0, stream>>>(attn, sraw, vt, tstats, ctx);
  } else {
    scores_kernel<false><<<1024, 256, 0, stream>>>(qh, kh, qnsqp, knsqp, sw,
                                                   attn, sraw, tstats);
    normalize_kernel<<<MQ, 256, 0, stream>>>(attn, tstats);
    pv_kernel<false><<<512, 512, 0, stream>>>(attn, sraw, vt, tstats, ctx);
  }
}